// Round 6
// baseline (448.427 us; speedup 1.0000x reference)
//
#include <hip/hip_runtime.h>
#include <hip/hip_bf16.h>
#include <cstdint>
#include <cstddef>

// Problem constants
#define B_    2
#define S_    2048
#define HID_  2048
#define H_    32
#define HKV_  8
#define DH_   64
// SCALE * log2(e): scores scaled into exp2 domain
#define SC2_  0.1803368801111244f
// Lazy-softmax fixed max (exp2 domain). Scores: std ~1.2, max(1.3e8) ~7.3.
// Softmax is shift-invariant; bf16/fp32 handle 2^(s-12) for any feasible s.
#define MFIX_ 12.0f

typedef __bf16 bf16;
typedef bf16  bf16x2 __attribute__((ext_vector_type(2)));
typedef bf16  bf16x4 __attribute__((ext_vector_type(4)));
typedef bf16  bf16x8 __attribute__((ext_vector_type(8)));
typedef float f32x4  __attribute__((ext_vector_type(4)));
typedef float f32x16 __attribute__((ext_vector_type(16)));

typedef __attribute__((address_space(3))) uint32_t  lds_u32_t;
typedef __attribute__((address_space(1))) const uint32_t glob_u32_t;

__device__ __forceinline__ void async16(const void* g, void* l) {
    __builtin_amdgcn_global_load_lds((glob_u32_t*)g, (lds_u32_t*)l, 16, 0, 0);
}

__device__ __forceinline__ bf16x8 cvt8(float4 a, float4 b) {
    bf16x8 r;
    r[0] = (bf16)a.x; r[1] = (bf16)a.y; r[2] = (bf16)a.z; r[3] = (bf16)a.w;
    r[4] = (bf16)b.x; r[5] = (bf16)b.y; r[6] = (bf16)b.z; r[7] = (bf16)b.w;
    return r;
}

__device__ __forceinline__ uint32_t pkbf(float a, float b) {
    bf16x2 t; t[0] = (bf16)a; t[1] = (bf16)b;
    return __builtin_bit_cast(uint32_t, t);
}
__device__ __forceinline__ bf16x8 mk8(uint32_t a, uint32_t b, uint32_t c, uint32_t d) {
    union { uint32_t u[4]; bf16x8 v; } t;
    t.u[0] = a; t.u[1] = b; t.u[2] = c; t.u[3] = d;
    return t.v;
}

// ---------------------------------------------------------------------------
// Merged fp32->bf16 convert for all 5 tensors (one launch).
// ---------------------------------------------------------------------------
__global__ __launch_bounds__(256) void cvt_all_kernel(
    const float* __restrict__ X,  const float* __restrict__ Wq,
    const float* __restrict__ Wk, const float* __restrict__ Wv,
    const float* __restrict__ Wo,
    bf16* __restrict__ Xb,  bf16* __restrict__ Wqb, bf16* __restrict__ Wkb,
    bf16* __restrict__ Wvb, bf16* __restrict__ Wob)
{
    const int i = blockIdx.x * 256 + threadIdx.x;
    const float* src; bf16* dst; int off;
    if (i < 1048576)      { src = X;  dst = Xb;  off = i; }
    else if (i < 1572864) { src = Wq; dst = Wqb; off = i - 1048576; }
    else if (i < 1703936) { src = Wk; dst = Wkb; off = i - 1572864; }
    else if (i < 1835008) { src = Wv; dst = Wvb; off = i - 1703936; }
    else                  { src = Wo; dst = Wob; off = i - 1835008; }
    float4 a = ((const float4*)src)[2 * off];
    float4 b = ((const float4*)src)[2 * off + 1];
    ((bf16x8*)dst)[off] = cvt8(a, b);
}

// ---------------------------------------------------------------------------
// Fused QKV projection GEMM (m97 structure). V written TRANSPOSED (b,hkv,d,s).
// ---------------------------------------------------------------------------
__global__ __launch_bounds__(256) void gemm_qkv_kernel(
    const bf16* __restrict__ A,
    const bf16* __restrict__ Wqb, const bf16* __restrict__ Wkb,
    const bf16* __restrict__ Wvb,
    const float* __restrict__ cs, const float* __restrict__ sn,
    bf16* __restrict__ Qo, bf16* __restrict__ Ko, bf16* __restrict__ Vt)
{
    __shared__ bf16 a_lds[128 * 64];
    __shared__ bf16 b_lds[128 * 64];

    const int tid  = threadIdx.x;
    const int wave = tid >> 6;
    const int lane = tid & 63;
    const int quad = lane >> 4;
    const int l16  = lane & 15;
    const int wm   = wave >> 1;
    const int wn   = wave & 1;
    const int m0   = blockIdx.x * 128;
    const int n0   = blockIdx.y * 128;

    f32x4 acc[4][4];
    #pragma unroll
    for (int mt = 0; mt < 4; ++mt)
        #pragma unroll
        for (int nt = 0; nt < 4; ++nt)
            acc[mt][nt] = (f32x4){0.f, 0.f, 0.f, 0.f};

    int srow[4], sgcol[4];
    const bf16* browp[4];
    #pragma unroll
    for (int i = 0; i < 4; ++i) {
        const int e = tid * 8 + i * 2048;
        srow[i] = e >> 6;
        const int chunk = (e >> 3) & 7;
        sgcol[i] = (chunk ^ (srow[i] & 7)) << 3;
        const int n = n0 + srow[i];
        browp[i] = (n < 2048) ? (Wqb + (size_t)n * HID_)
                 : (n < 2560) ? (Wkb + (size_t)(n - 2048) * HID_)
                              : (Wvb + (size_t)(n - 2560) * HID_);
    }

    for (int k0 = 0; k0 < HID_; k0 += 64) {
        #pragma unroll
        for (int i = 0; i < 4; ++i) {
            async16(A + (size_t)(m0 + srow[i]) * HID_ + k0 + sgcol[i],
                    &a_lds[tid * 8 + i * 2048]);
            async16(browp[i] + k0 + sgcol[i],
                    &b_lds[tid * 8 + i * 2048]);
        }
        __syncthreads();
        #pragma unroll
        for (int ks = 0; ks < 2; ++ks) {
            bf16x8 af[4], bfr[4];
            #pragma unroll
            for (int mt = 0; mt < 4; ++mt) {
                const int row = wm * 64 + mt * 16 + l16;
                const int c = (ks * 4 + quad) ^ (row & 7);
                af[mt] = *(const bf16x8*)(&a_lds[row * 64 + c * 8]);
            }
            #pragma unroll
            for (int nt = 0; nt < 4; ++nt) {
                const int row = wn * 64 + nt * 16 + l16;
                const int c = (ks * 4 + quad) ^ (row & 7);
                bfr[nt] = *(const bf16x8*)(&b_lds[row * 64 + c * 8]);
            }
            #pragma unroll
            for (int mt = 0; mt < 4; ++mt)
                #pragma unroll
                for (int nt = 0; nt < 4; ++nt)
                    acc[mt][nt] = __builtin_amdgcn_mfma_f32_16x16x32_bf16(
                        af[mt], bfr[nt], acc[mt][nt], 0, 0, 0);
        }
        __syncthreads();
    }

    const int nw = n0 + wn * 64;
    const int d  = l16;
    #pragma unroll
    for (int mt = 0; mt < 4; ++mt) {
        #pragma unroll
        for (int r = 0; r < 4; ++r) {
            const int m  = m0 + wm * 64 + mt * 16 + quad * 4 + r;
            const int bb = m >> 11;
            const int ss = m & (S_ - 1);
            const float v0 = acc[mt][0][r], v1 = acc[mt][1][r];
            const float v2 = acc[mt][2][r], v3 = acc[mt][3][r];
            if (nw < 2048) {
                const int h = nw >> 6;
                bf16* dp = Qo + ((size_t)(bb * H_ + h) * S_ + ss) * DH_;
                const float* cp = cs + ((size_t)bb * S_ + ss) * DH_;
                const float* sp = sn + ((size_t)bb * S_ + ss) * DH_;
                dp[ 0 + d] = (bf16)(v0 * cp[ 0 + d] - v2 * sp[ 0 + d]);
                dp[16 + d] = (bf16)(v1 * cp[16 + d] - v3 * sp[16 + d]);
                dp[32 + d] = (bf16)(v2 * cp[32 + d] + v0 * sp[32 + d]);
                dp[48 + d] = (bf16)(v3 * cp[48 + d] + v1 * sp[48 + d]);
            } else if (nw < 2560) {
                const int h = (nw - 2048) >> 6;
                bf16* dp = Ko + ((size_t)(bb * HKV_ + h) * S_ + ss) * DH_;
                const float* cp = cs + ((size_t)bb * S_ + ss) * DH_;
                const float* sp = sn + ((size_t)bb * S_ + ss) * DH_;
                dp[ 0 + d] = (bf16)(v0 * cp[ 0 + d] - v2 * sp[ 0 + d]);
                dp[16 + d] = (bf16)(v1 * cp[16 + d] - v3 * sp[16 + d]);
                dp[32 + d] = (bf16)(v2 * cp[32 + d] + v0 * sp[32 + d]);
                dp[48 + d] = (bf16)(v3 * cp[48 + d] + v1 * sp[48 + d]);
            } else {
                const int h = (nw - 2560) >> 6;
                bf16* dp = Vt + ((size_t)(bb * HKV_ + h) * DH_) * S_ + ss;
                dp[(size_t)( 0 + d) * S_] = (bf16)v0;
                dp[(size_t)(16 + d) * S_] = (bf16)v1;
                dp[(size_t)(32 + d) * S_] = (bf16)v2;
                dp[(size_t)(48 + d) * S_] = (bf16)v3;
            }
        }
    }
}

// ---------------------------------------------------------------------------
// Output projection: Y (4096 x 2048 fp32) = Ob (bf16, (b,s,h*d)) * Wob^T.
// ---------------------------------------------------------------------------
__global__ __launch_bounds__(256) void gemm_out_kernel(
    const bf16* __restrict__ A, const bf16* __restrict__ Wb,
    float* __restrict__ Y)
{
    __shared__ bf16 a_lds[128 * 64];
    __shared__ bf16 b_lds[128 * 64];

    const int tid  = threadIdx.x;
    const int wave = tid >> 6;
    const int lane = tid & 63;
    const int quad = lane >> 4;
    const int l16  = lane & 15;
    const int wm   = wave >> 1;
    const int wn   = wave & 1;
    const int m0   = blockIdx.x * 128;
    const int n0   = blockIdx.y * 128;

    f32x4 acc[4][4];
    #pragma unroll
    for (int mt = 0; mt < 4; ++mt)
        #pragma unroll
        for (int nt = 0; nt < 4; ++nt)
            acc[mt][nt] = (f32x4){0.f, 0.f, 0.f, 0.f};

    int srow[4], sgcol[4];
    #pragma unroll
    for (int i = 0; i < 4; ++i) {
        const int e = tid * 8 + i * 2048;
        srow[i] = e >> 6;
        const int chunk = (e >> 3) & 7;
        sgcol[i] = (chunk ^ (srow[i] & 7)) << 3;
    }

    for (int k0 = 0; k0 < HID_; k0 += 64) {
        #pragma unroll
        for (int i = 0; i < 4; ++i) {
            async16(A + (size_t)(m0 + srow[i]) * HID_ + k0 + sgcol[i],
                    &a_lds[tid * 8 + i * 2048]);
            async16(Wb + (size_t)(n0 + srow[i]) * HID_ + k0 + sgcol[i],
                    &b_lds[tid * 8 + i * 2048]);
        }
        __syncthreads();
        #pragma unroll
        for (int ks = 0; ks < 2; ++ks) {
            bf16x8 af[4], bfr[4];
            #pragma unroll
            for (int mt = 0; mt < 4; ++mt) {
                const int row = wm * 64 + mt * 16 + l16;
                const int c = (ks * 4 + quad) ^ (row & 7);
                af[mt] = *(const bf16x8*)(&a_lds[row * 64 + c * 8]);
            }
            #pragma unroll
            for (int nt = 0; nt < 4; ++nt) {
                const int row = wn * 64 + nt * 16 + l16;
                const int c = (ks * 4 + quad) ^ (row & 7);
                bfr[nt] = *(const bf16x8*)(&b_lds[row * 64 + c * 8]);
            }
            #pragma unroll
            for (int mt = 0; mt < 4; ++mt)
                #pragma unroll
                for (int nt = 0; nt < 4; ++nt)
                    acc[mt][nt] = __builtin_amdgcn_mfma_f32_16x16x32_bf16(
                        af[mt], bfr[nt], acc[mt][nt], 0, 0, 0);
        }
        __syncthreads();
    }

    #pragma unroll
    for (int mt = 0; mt < 4; ++mt)
        #pragma unroll
        for (int nt = 0; nt < 4; ++nt)
            #pragma unroll
            for (int r = 0; r < 4; ++r) {
                const int m = m0 + wm * 64 + mt * 16 + quad * 4 + r;
                const int n = n0 + wn * 64 + nt * 16 + l16;
                Y[(size_t)m * HID_ + n] = acc[mt][nt][r];
            }
}

// ---------------------------------------------------------------------------
// Flash attention v5 (causal, GQA), 32x32x16 MFMA, LAZY SOFTMAX.
// QK swapped -> S^T (col=q=lane&31); PV swapped -> O^T (col=q).
// Lazy softmax: fixed max MFIX_ in exp2 domain (shift-invariant => exact);
// no running max, no alpha, no o_acc rescale; l summed per-lane, one
// cross-half reduce in the epilogue.
// P C-layout -> B-layout via cross-half shfl_xor register exchange.
// K/V^T double-buffered LDS, 1 barrier/iter. Grid 1024 blocks (qt reversed,
// longest first) -> 4 blocks/CU, 4 waves/SIMD for chain overlap.
// ---------------------------------------------------------------------------
__global__ __launch_bounds__(256, 4) void attn_kernel(
    const bf16* __restrict__ Q, const bf16* __restrict__ K,
    const bf16* __restrict__ Vt, bf16* __restrict__ O)
{
    __shared__ bf16 k_lds[2][64 * 64];
    __shared__ bf16 v_lds[2][64 * 64];

    const int tid  = threadIdx.x;
    const int wave = tid >> 6;
    const int lane = tid & 63;
    const int l32  = lane & 31;
    const int half = lane >> 5;
    const int qt = 15 - (int)blockIdx.x;
    const int h  = blockIdx.y;
    const int b  = blockIdx.z;
    const int hkv = h >> 2;
    const int q0  = qt * 128;
    const int qb0 = q0 + wave * 32;
    const int qa  = qb0 + l32;

    const bf16* Qg = Q  + (size_t)(b * H_ + h) * S_ * DH_;
    const bf16* Kg = K  + (size_t)(b * HKV_ + hkv) * S_ * DH_;
    const bf16* Vg = Vt + ((size_t)(b * HKV_ + hkv) * DH_) * S_;

    const int srow0  = tid >> 3;
    const int scolsw = ((tid & 7) ^ ((tid >> 3) & 7)) << 3;

    // Q fragments, B-layout: n=l32 -> q, k = c*16 + half*8 + j -> dh
    bf16x8 qf[4];
    #pragma unroll
    for (int c = 0; c < 4; ++c)
        qf[c] = *(const bf16x8*)(Qg + (size_t)(qb0 + l32) * DH_ + c * 16 + half * 8);

    f32x16 o_acc[2];
    #pragma unroll
    for (int dt = 0; dt < 2; ++dt)
        #pragma unroll
        for (int e = 0; e < 16; ++e) o_acc[dt][e] = 0.f;
    float l_i = 0.f;

    const int nkt = 2 * qt + 2;

    // prefetch tile 0
    #pragma unroll
    for (int i = 0; i < 2; ++i) {
        const int row = srow0 + i * 32;
        async16(Kg + (size_t)row * DH_ + scolsw, &k_lds[0][tid * 8 + i * 2048]);
        async16(Vg + (size_t)row * S_  + scolsw, &v_lds[0][tid * 8 + i * 2048]);
    }
    __syncthreads();

    for (int kt = 0; kt < nkt; ++kt) {
        if (kt + 1 < nkt) {
            bf16* kb = k_lds[(kt + 1) & 1];
            bf16* vb = v_lds[(kt + 1) & 1];
            #pragma unroll
            for (int i = 0; i < 2; ++i) {
                const int row = srow0 + i * 32;
                async16(Kg + (size_t)((kt + 1) * 64 + row) * DH_ + scolsw,
                        kb + tid * 8 + i * 2048);
                async16(Vg + (size_t)row * S_ + (kt + 1) * 64 + scolsw,
                        vb + tid * 8 + i * 2048);
            }
        }

        if (kt * 64 <= qb0 + 31) {
            const bf16* kb = k_lds[kt & 1];
            const bf16* vb = v_lds[kt & 1];
            const bool act1 = (kt * 64 + 32) <= (qb0 + 31);

            // V^T A-frags
            bf16x8 vf[2][4];
            #pragma unroll
            for (int dt = 0; dt < 2; ++dt)
                #pragma unroll
                for (int c = 0; c < 4; ++c) {
                    const int row = dt * 32 + l32;
                    const int col = ((2 * c + half) ^ (row & 7)) << 3;
                    vf[dt][c] = *(const bf16x8*)(vb + row * 64 + col);
                }

            // scores
            f32x16 s0, s1;
            {
                bf16x8 kf[4];
                #pragma unroll
                for (int c = 0; c < 4; ++c) {
                    const int col = ((2 * c + half) ^ (l32 & 7)) << 3;
                    kf[c] = *(const bf16x8*)(kb + l32 * 64 + col);
                }
                f32x16 a;
                #pragma unroll
                for (int e = 0; e < 16; ++e) a[e] = 0.f;
                #pragma unroll
                for (int c = 0; c < 4; ++c)
                    a = __builtin_amdgcn_mfma_f32_32x32x16_bf16(kf[c], qf[c], a, 0, 0, 0);
                s0 = a;
            }
            if (act1) {
                bf16x8 kf[4];
                #pragma unroll
                for (int c = 0; c < 4; ++c) {
                    const int row = 32 + l32;
                    const int col = ((2 * c + half) ^ (row & 7)) << 3;
                    kf[c] = *(const bf16x8*)(kb + row * 64 + col);
                }
                f32x16 a;
                #pragma unroll
                for (int e = 0; e < 16; ++e) a[e] = 0.f;
                #pragma unroll
                for (int c = 0; c < 4; ++c)
                    a = __builtin_amdgcn_mfma_f32_32x32x16_bf16(kf[c], qf[c], a, 0, 0, 0);
                s1 = a;
            }

            // lazy softmax: p = exp2(s*SC2 - MFIX), mask diag tiles to 0
            const bool full0 = (kt * 64 + 31) <= qb0;
            float sm = 0.f;
            #pragma unroll
            for (int e = 0; e < 16; ++e) {
                float p = __builtin_amdgcn_exp2f(s0[e] * SC2_ - MFIX_);
                if (!full0) {
                    const int kp = kt * 64 + (e & 3) + 8 * (e >> 2) + 4 * half;
                    p = (kp <= qa) ? p : 0.f;
                }
                s0[e] = p; sm += p;
            }
            if (act1) {
                const bool full1 = (kt * 64 + 63) <= qb0;
                #pragma unroll
                for (int e = 0; e < 16; ++e) {
                    float p = __builtin_amdgcn_exp2f(s1[e] * SC2_ - MFIX_);
                    if (!full1) {
                        const int kp = kt * 64 + 32 + (e & 3) + 8 * (e >> 2) + 4 * half;
                        p = (kp <= qa) ? p : 0.f;
                    }
                    s1[e] = p; sm += p;
                }
            }
            l_i += sm;

            // P: C-layout -> B-layout via cross-half register exchange
            bf16x8 pf[4];
            {
                uint32_t d0 = pkbf(s0[0],  s0[1]),  d1 = pkbf(s0[2],  s0[3]);
                uint32_t d2 = pkbf(s0[4],  s0[5]),  d3 = pkbf(s0[6],  s0[7]);
                uint32_t d4 = pkbf(s0[8],  s0[9]),  d5 = pkbf(s0[10], s0[11]);
                uint32_t d6 = pkbf(s0[12], s0[13]), d7 = pkbf(s0[14], s0[15]);
                uint32_t x0 = __shfl_xor((int)d0, 32), x1 = __shfl_xor((int)d1, 32);
                uint32_t x2 = __shfl_xor((int)d2, 32), x3 = __shfl_xor((int)d3, 32);
                uint32_t x4 = __shfl_xor((int)d4, 32), x5 = __shfl_xor((int)d5, 32);
                uint32_t x6 = __shfl_xor((int)d6, 32), x7 = __shfl_xor((int)d7, 32);
                pf[0] = half ? mk8(x2, x3, d2, d3) : mk8(d0, d1, x0, x1);
                pf[1] = half ? mk8(x6, x7, d6, d7) : mk8(d4, d5, x4, x5);
            }
            if (act1) {
                uint32_t d0 = pkbf(s1[0],  s1[1]),  d1 = pkbf(s1[2],  s1[3]);
                uint32_t d2 = pkbf(s1[4],  s1[5]),  d3 = pkbf(s1[6],  s1[7]);
                uint32_t d4 = pkbf(s1[8],  s1[9]),  d5 = pkbf(s1[10], s1[11]);
                uint32_t d6 = pkbf(s1[12], s1[13]), d7 = pkbf(s1[14], s1[15]);
                uint32_t x0 = __shfl_xor((int)d0, 32), x1 = __shfl_xor((int)d1, 32);
                uint32_t x2 = __shfl_xor((int)d2, 32), x3 = __shfl_xor((int)d3, 32);
                uint32_t x4 = __shfl_xor((int)d4, 32), x5 = __shfl_xor((int)d5, 32);
                uint32_t x6 = __shfl_xor((int)d6, 32), x7 = __shfl_xor((int)d7, 32);
                pf[2] = half ? mk8(x2, x3, d2, d3) : mk8(d0, d1, x0, x1);
                pf[3] = half ? mk8(x6, x7, d6, d7) : mk8(d4, d5, x4, x5);
            }

            // O^T += V^T * P^T
            const int nc = act1 ? 4 : 2;
            #pragma unroll
            for (int c = 0; c < 4; ++c) {
                if (c >= nc) break;
                #pragma unroll
                for (int dt = 0; dt < 2; ++dt)
                    o_acc[dt] = __builtin_amdgcn_mfma_f32_32x32x16_bf16(
                        vf[dt][c], pf[c], o_acc[dt], 0, 0, 0);
            }
        }
        __syncthreads();
    }

    // epilogue: combine halves of l once, normalize, store O (b, s, h*64+d)
    const float lt = l_i + __shfl_xor(l_i, 32);
    const float inv = 1.f / lt;
    bf16* op = O + ((size_t)(b * S_ + qa) * H_ + h) * DH_;
    #pragma unroll
    for (int dt = 0; dt < 2; ++dt)
        #pragma unroll
        for (int g = 0; g < 4; ++g) {
            bf16x4 ov;
            #pragma unroll
            for (int r = 0; r < 4; ++r) ov[r] = (bf16)(o_acc[dt][g * 4 + r] * inv);
            *(bf16x4*)(op + dt * 32 + g * 8 + half * 4) = ov;
        }
}

// ---------------------------------------------------------------------------
extern "C" void kernel_launch(void* const* d_in, const int* in_sizes, int n_in,
                              void* d_out, int out_size, void* d_ws, size_t ws_size,
                              hipStream_t stream)
{
    const float* X    = (const float*)d_in[0];
    const float* cs   = (const float*)d_in[1];
    const float* sn   = (const float*)d_in[2];
    const float* Wq   = (const float*)d_in[4];
    const float* Wk   = (const float*)d_in[5];
    const float* Wv   = (const float*)d_in[6];
    const float* Wo   = (const float*)d_in[7];
    float* Y          = (float*)d_out;

    bf16* Xb  = (bf16*)d_ws;                       // 8388608
    bf16* Wqb = Xb  + (size_t)8388608;             // 4194304
    bf16* Wkb = Wqb + (size_t)4194304;             // 1048576
    bf16* Wvb = Wkb + (size_t)1048576;             // 1048576
    bf16* Wob = Wvb + (size_t)1048576;             // 4194304
    bf16* Qb  = Wob + (size_t)4194304;             // 8388608
    bf16* Kb  = Qb  + (size_t)8388608;             // 2097152
    bf16* Vtb = Kb  + (size_t)2097152;             // 2097152 (transposed d,s)
    bf16* Ob  = Vtb + (size_t)2097152;             // 8388608

    dim3 blk(256);
    cvt_all_kernel<<<dim3(9216), blk, 0, stream>>>(X, Wq, Wk, Wv, Wo,
                                                   Xb, Wqb, Wkb, Wvb, Wob);
    gemm_qkv_kernel<<<dim3(32, 24), blk, 0, stream>>>(Xb, Wqb, Wkb, Wvb,
                                                      cs, sn, Qb, Kb, Vtb);
    attn_kernel<<<dim3(16, H_, B_), blk, 0, stream>>>(Qb, Kb, Vtb, Ob);
    gemm_out_kernel<<<dim3(32, 16), blk, 0, stream>>>(Ob, Wob, Y);
}

// Round 7
// 406.032 us; speedup vs baseline: 1.1044x; 1.1044x over previous
//
#include <hip/hip_runtime.h>
#include <hip/hip_bf16.h>
#include <cstdint>
#include <cstddef>

// Problem constants
#define B_    2
#define S_    2048
#define HID_  2048
#define H_    32
#define HKV_  8
#define DH_   64
// SCALE * log2(e): scores scaled into exp2 domain
#define SC2_  0.1803368801111244f
// Lazy-softmax fixed max (exp2 domain). Scores: std ~1.2, max(1.3e8) ~7.3.
// Softmax is shift-invariant; fp32 handles 2^(s-12) for any feasible s.
#define MFIX_ 12.0f

typedef __bf16 bf16;
typedef bf16  bf16x2 __attribute__((ext_vector_type(2)));
typedef bf16  bf16x4 __attribute__((ext_vector_type(4)));
typedef bf16  bf16x8 __attribute__((ext_vector_type(8)));
typedef float f32x4  __attribute__((ext_vector_type(4)));
typedef float f32x16 __attribute__((ext_vector_type(16)));

typedef __attribute__((address_space(3))) uint32_t  lds_u32_t;
typedef __attribute__((address_space(1))) const uint32_t glob_u32_t;

__device__ __forceinline__ void async16(const void* g, void* l) {
    __builtin_amdgcn_global_load_lds((glob_u32_t*)g, (lds_u32_t*)l, 16, 0, 0);
}

__device__ __forceinline__ bf16x8 cvt8(float4 a, float4 b) {
    bf16x8 r;
    r[0] = (bf16)a.x; r[1] = (bf16)a.y; r[2] = (bf16)a.z; r[3] = (bf16)a.w;
    r[4] = (bf16)b.x; r[5] = (bf16)b.y; r[6] = (bf16)b.z; r[7] = (bf16)b.w;
    return r;
}

__device__ __forceinline__ uint32_t pkbf(float a, float b) {
    bf16x2 t; t[0] = (bf16)a; t[1] = (bf16)b;
    return __builtin_bit_cast(uint32_t, t);
}
__device__ __forceinline__ bf16x8 mk8(uint32_t a, uint32_t b, uint32_t c, uint32_t d) {
    union { uint32_t u[4]; bf16x8 v; } t;
    t.u[0] = a; t.u[1] = b; t.u[2] = c; t.u[3] = d;
    return t.v;
}

// ---------------------------------------------------------------------------
// Merged fp32->bf16 convert for all 5 tensors (one launch).
// ---------------------------------------------------------------------------
__global__ __launch_bounds__(256) void cvt_all_kernel(
    const float* __restrict__ X,  const float* __restrict__ Wq,
    const float* __restrict__ Wk, const float* __restrict__ Wv,
    const float* __restrict__ Wo,
    bf16* __restrict__ Xb,  bf16* __restrict__ Wqb, bf16* __restrict__ Wkb,
    bf16* __restrict__ Wvb, bf16* __restrict__ Wob)
{
    const int i = blockIdx.x * 256 + threadIdx.x;
    const float* src; bf16* dst; int off;
    if (i < 1048576)      { src = X;  dst = Xb;  off = i; }
    else if (i < 1572864) { src = Wq; dst = Wqb; off = i - 1048576; }
    else if (i < 1703936) { src = Wk; dst = Wkb; off = i - 1572864; }
    else if (i < 1835008) { src = Wv; dst = Wvb; off = i - 1703936; }
    else                  { src = Wo; dst = Wob; off = i - 1835008; }
    float4 a = ((const float4*)src)[2 * off];
    float4 b = ((const float4*)src)[2 * off + 1];
    ((bf16x8*)dst)[off] = cvt8(a, b);
}

// ---------------------------------------------------------------------------
// Fused QKV projection GEMM (m97 structure). V written TRANSPOSED (b,hkv,d,s).
// ---------------------------------------------------------------------------
__global__ __launch_bounds__(256) void gemm_qkv_kernel(
    const bf16* __restrict__ A,
    const bf16* __restrict__ Wqb, const bf16* __restrict__ Wkb,
    const bf16* __restrict__ Wvb,
    const float* __restrict__ cs, const float* __restrict__ sn,
    bf16* __restrict__ Qo, bf16* __restrict__ Ko, bf16* __restrict__ Vt)
{
    __shared__ bf16 a_lds[128 * 64];
    __shared__ bf16 b_lds[128 * 64];

    const int tid  = threadIdx.x;
    const int wave = tid >> 6;
    const int lane = tid & 63;
    const int quad = lane >> 4;
    const int l16  = lane & 15;
    const int wm   = wave >> 1;
    const int wn   = wave & 1;
    const int m0   = blockIdx.x * 128;
    const int n0   = blockIdx.y * 128;

    f32x4 acc[4][4];
    #pragma unroll
    for (int mt = 0; mt < 4; ++mt)
        #pragma unroll
        for (int nt = 0; nt < 4; ++nt)
            acc[mt][nt] = (f32x4){0.f, 0.f, 0.f, 0.f};

    int srow[4], sgcol[4];
    const bf16* browp[4];
    #pragma unroll
    for (int i = 0; i < 4; ++i) {
        const int e = tid * 8 + i * 2048;
        srow[i] = e >> 6;
        const int chunk = (e >> 3) & 7;
        sgcol[i] = (chunk ^ (srow[i] & 7)) << 3;
        const int n = n0 + srow[i];
        browp[i] = (n < 2048) ? (Wqb + (size_t)n * HID_)
                 : (n < 2560) ? (Wkb + (size_t)(n - 2048) * HID_)
                              : (Wvb + (size_t)(n - 2560) * HID_);
    }

    for (int k0 = 0; k0 < HID_; k0 += 64) {
        #pragma unroll
        for (int i = 0; i < 4; ++i) {
            async16(A + (size_t)(m0 + srow[i]) * HID_ + k0 + sgcol[i],
                    &a_lds[tid * 8 + i * 2048]);
            async16(browp[i] + k0 + sgcol[i],
                    &b_lds[tid * 8 + i * 2048]);
        }
        __syncthreads();
        #pragma unroll
        for (int ks = 0; ks < 2; ++ks) {
            bf16x8 af[4], bfr[4];
            #pragma unroll
            for (int mt = 0; mt < 4; ++mt) {
                const int row = wm * 64 + mt * 16 + l16;
                const int c = (ks * 4 + quad) ^ (row & 7);
                af[mt] = *(const bf16x8*)(&a_lds[row * 64 + c * 8]);
            }
            #pragma unroll
            for (int nt = 0; nt < 4; ++nt) {
                const int row = wn * 64 + nt * 16 + l16;
                const int c = (ks * 4 + quad) ^ (row & 7);
                bfr[nt] = *(const bf16x8*)(&b_lds[row * 64 + c * 8]);
            }
            #pragma unroll
            for (int mt = 0; mt < 4; ++mt)
                #pragma unroll
                for (int nt = 0; nt < 4; ++nt)
                    acc[mt][nt] = __builtin_amdgcn_mfma_f32_16x16x32_bf16(
                        af[mt], bfr[nt], acc[mt][nt], 0, 0, 0);
        }
        __syncthreads();
    }

    const int nw = n0 + wn * 64;
    const int d  = l16;
    #pragma unroll
    for (int mt = 0; mt < 4; ++mt) {
        #pragma unroll
        for (int r = 0; r < 4; ++r) {
            const int m  = m0 + wm * 64 + mt * 16 + quad * 4 + r;
            const int bb = m >> 11;
            const int ss = m & (S_ - 1);
            const float v0 = acc[mt][0][r], v1 = acc[mt][1][r];
            const float v2 = acc[mt][2][r], v3 = acc[mt][3][r];
            if (nw < 2048) {
                const int h = nw >> 6;
                bf16* dp = Qo + ((size_t)(bb * H_ + h) * S_ + ss) * DH_;
                const float* cp = cs + ((size_t)bb * S_ + ss) * DH_;
                const float* sp = sn + ((size_t)bb * S_ + ss) * DH_;
                dp[ 0 + d] = (bf16)(v0 * cp[ 0 + d] - v2 * sp[ 0 + d]);
                dp[16 + d] = (bf16)(v1 * cp[16 + d] - v3 * sp[16 + d]);
                dp[32 + d] = (bf16)(v2 * cp[32 + d] + v0 * sp[32 + d]);
                dp[48 + d] = (bf16)(v3 * cp[48 + d] + v1 * sp[48 + d]);
            } else if (nw < 2560) {
                const int h = (nw - 2048) >> 6;
                bf16* dp = Ko + ((size_t)(bb * HKV_ + h) * S_ + ss) * DH_;
                const float* cp = cs + ((size_t)bb * S_ + ss) * DH_;
                const float* sp = sn + ((size_t)bb * S_ + ss) * DH_;
                dp[ 0 + d] = (bf16)(v0 * cp[ 0 + d] - v2 * sp[ 0 + d]);
                dp[16 + d] = (bf16)(v1 * cp[16 + d] - v3 * sp[16 + d]);
                dp[32 + d] = (bf16)(v2 * cp[32 + d] + v0 * sp[32 + d]);
                dp[48 + d] = (bf16)(v3 * cp[48 + d] + v1 * sp[48 + d]);
            } else {
                const int h = (nw - 2560) >> 6;
                bf16* dp = Vt + ((size_t)(bb * HKV_ + h) * DH_) * S_ + ss;
                dp[(size_t)( 0 + d) * S_] = (bf16)v0;
                dp[(size_t)(16 + d) * S_] = (bf16)v1;
                dp[(size_t)(32 + d) * S_] = (bf16)v2;
                dp[(size_t)(48 + d) * S_] = (bf16)v3;
            }
        }
    }
}

// ---------------------------------------------------------------------------
// Output projection: Y (4096 x 2048 fp32) = Ob (bf16, (b,s,h*d)) * Wob^T.
// ---------------------------------------------------------------------------
__global__ __launch_bounds__(256) void gemm_out_kernel(
    const bf16* __restrict__ A, const bf16* __restrict__ Wb,
    float* __restrict__ Y)
{
    __shared__ bf16 a_lds[128 * 64];
    __shared__ bf16 b_lds[128 * 64];

    const int tid  = threadIdx.x;
    const int wave = tid >> 6;
    const int lane = tid & 63;
    const int quad = lane >> 4;
    const int l16  = lane & 15;
    const int wm   = wave >> 1;
    const int wn   = wave & 1;
    const int m0   = blockIdx.x * 128;
    const int n0   = blockIdx.y * 128;

    f32x4 acc[4][4];
    #pragma unroll
    for (int mt = 0; mt < 4; ++mt)
        #pragma unroll
        for (int nt = 0; nt < 4; ++nt)
            acc[mt][nt] = (f32x4){0.f, 0.f, 0.f, 0.f};

    int srow[4], sgcol[4];
    #pragma unroll
    for (int i = 0; i < 4; ++i) {
        const int e = tid * 8 + i * 2048;
        srow[i] = e >> 6;
        const int chunk = (e >> 3) & 7;
        sgcol[i] = (chunk ^ (srow[i] & 7)) << 3;
    }

    for (int k0 = 0; k0 < HID_; k0 += 64) {
        #pragma unroll
        for (int i = 0; i < 4; ++i) {
            async16(A + (size_t)(m0 + srow[i]) * HID_ + k0 + sgcol[i],
                    &a_lds[tid * 8 + i * 2048]);
            async16(Wb + (size_t)(n0 + srow[i]) * HID_ + k0 + sgcol[i],
                    &b_lds[tid * 8 + i * 2048]);
        }
        __syncthreads();
        #pragma unroll
        for (int ks = 0; ks < 2; ++ks) {
            bf16x8 af[4], bfr[4];
            #pragma unroll
            for (int mt = 0; mt < 4; ++mt) {
                const int row = wm * 64 + mt * 16 + l16;
                const int c = (ks * 4 + quad) ^ (row & 7);
                af[mt] = *(const bf16x8*)(&a_lds[row * 64 + c * 8]);
            }
            #pragma unroll
            for (int nt = 0; nt < 4; ++nt) {
                const int row = wn * 64 + nt * 16 + l16;
                const int c = (ks * 4 + quad) ^ (row & 7);
                bfr[nt] = *(const bf16x8*)(&b_lds[row * 64 + c * 8]);
            }
            #pragma unroll
            for (int mt = 0; mt < 4; ++mt)
                #pragma unroll
                for (int nt = 0; nt < 4; ++nt)
                    acc[mt][nt] = __builtin_amdgcn_mfma_f32_16x16x32_bf16(
                        af[mt], bfr[nt], acc[mt][nt], 0, 0, 0);
        }
        __syncthreads();
    }

    #pragma unroll
    for (int mt = 0; mt < 4; ++mt)
        #pragma unroll
        for (int nt = 0; nt < 4; ++nt)
            #pragma unroll
            for (int r = 0; r < 4; ++r) {
                const int m = m0 + wm * 64 + mt * 16 + quad * 4 + r;
                const int n = n0 + wn * 64 + nt * 16 + l16;
                Y[(size_t)m * HID_ + n] = acc[mt][nt][r];
            }
}

// ---------------------------------------------------------------------------
// Flash attention v5b (causal, GQA), 32x32x16 MFMA, LAZY SOFTMAX.
// Same as v5 but NO min-waves launch bound: round 6's (256,4) forced
// VGPR 128->64 and spilled to scratch (WRITE_SIZE 16->44 MB, 2x dur).
// Plain (256) lets the allocator land ~128 VGPR => 4 waves/SIMD at no spill.
// ---------------------------------------------------------------------------
__global__ __launch_bounds__(256) void attn_kernel(
    const bf16* __restrict__ Q, const bf16* __restrict__ K,
    const bf16* __restrict__ Vt, bf16* __restrict__ O)
{
    __shared__ bf16 k_lds[2][64 * 64];
    __shared__ bf16 v_lds[2][64 * 64];

    const int tid  = threadIdx.x;
    const int wave = tid >> 6;
    const int lane = tid & 63;
    const int l32  = lane & 31;
    const int half = lane >> 5;
    const int qt = 15 - (int)blockIdx.x;
    const int h  = blockIdx.y;
    const int b  = blockIdx.z;
    const int hkv = h >> 2;
    const int q0  = qt * 128;
    const int qb0 = q0 + wave * 32;
    const int qa  = qb0 + l32;

    const bf16* Qg = Q  + (size_t)(b * H_ + h) * S_ * DH_;
    const bf16* Kg = K  + (size_t)(b * HKV_ + hkv) * S_ * DH_;
    const bf16* Vg = Vt + ((size_t)(b * HKV_ + hkv) * DH_) * S_;

    const int srow0  = tid >> 3;
    const int scolsw = ((tid & 7) ^ ((tid >> 3) & 7)) << 3;

    // Q fragments, B-layout: n=l32 -> q, k = c*16 + half*8 + j -> dh
    bf16x8 qf[4];
    #pragma unroll
    for (int c = 0; c < 4; ++c)
        qf[c] = *(const bf16x8*)(Qg + (size_t)(qb0 + l32) * DH_ + c * 16 + half * 8);

    f32x16 o_acc[2];
    #pragma unroll
    for (int dt = 0; dt < 2; ++dt)
        #pragma unroll
        for (int e = 0; e < 16; ++e) o_acc[dt][e] = 0.f;
    float l_i = 0.f;

    const int nkt = 2 * qt + 2;

    // prefetch tile 0
    #pragma unroll
    for (int i = 0; i < 2; ++i) {
        const int row = srow0 + i * 32;
        async16(Kg + (size_t)row * DH_ + scolsw, &k_lds[0][tid * 8 + i * 2048]);
        async16(Vg + (size_t)row * S_  + scolsw, &v_lds[0][tid * 8 + i * 2048]);
    }
    __syncthreads();

    for (int kt = 0; kt < nkt; ++kt) {
        if (kt + 1 < nkt) {
            bf16* kb = k_lds[(kt + 1) & 1];
            bf16* vb = v_lds[(kt + 1) & 1];
            #pragma unroll
            for (int i = 0; i < 2; ++i) {
                const int row = srow0 + i * 32;
                async16(Kg + (size_t)((kt + 1) * 64 + row) * DH_ + scolsw,
                        kb + tid * 8 + i * 2048);
                async16(Vg + (size_t)row * S_ + (kt + 1) * 64 + scolsw,
                        vb + tid * 8 + i * 2048);
            }
        }

        if (kt * 64 <= qb0 + 31) {
            const bf16* kb = k_lds[kt & 1];
            const bf16* vb = v_lds[kt & 1];
            const bool act1 = (kt * 64 + 32) <= (qb0 + 31);

            // V^T A-frags
            bf16x8 vf[2][4];
            #pragma unroll
            for (int dt = 0; dt < 2; ++dt)
                #pragma unroll
                for (int c = 0; c < 4; ++c) {
                    const int row = dt * 32 + l32;
                    const int col = ((2 * c + half) ^ (row & 7)) << 3;
                    vf[dt][c] = *(const bf16x8*)(vb + row * 64 + col);
                }

            // scores
            f32x16 s0, s1;
            {
                bf16x8 kf[4];
                #pragma unroll
                for (int c = 0; c < 4; ++c) {
                    const int col = ((2 * c + half) ^ (l32 & 7)) << 3;
                    kf[c] = *(const bf16x8*)(kb + l32 * 64 + col);
                }
                f32x16 a;
                #pragma unroll
                for (int e = 0; e < 16; ++e) a[e] = 0.f;
                #pragma unroll
                for (int c = 0; c < 4; ++c)
                    a = __builtin_amdgcn_mfma_f32_32x32x16_bf16(kf[c], qf[c], a, 0, 0, 0);
                s0 = a;
            }
            if (act1) {
                bf16x8 kf[4];
                #pragma unroll
                for (int c = 0; c < 4; ++c) {
                    const int row = 32 + l32;
                    const int col = ((2 * c + half) ^ (row & 7)) << 3;
                    kf[c] = *(const bf16x8*)(kb + row * 64 + col);
                }
                f32x16 a;
                #pragma unroll
                for (int e = 0; e < 16; ++e) a[e] = 0.f;
                #pragma unroll
                for (int c = 0; c < 4; ++c)
                    a = __builtin_amdgcn_mfma_f32_32x32x16_bf16(kf[c], qf[c], a, 0, 0, 0);
                s1 = a;
            }

            // lazy softmax: p = exp2(s*SC2 - MFIX), mask diag tiles to 0
            const bool full0 = (kt * 64 + 31) <= qb0;
            float sm = 0.f;
            #pragma unroll
            for (int e = 0; e < 16; ++e) {
                float p = __builtin_amdgcn_exp2f(s0[e] * SC2_ - MFIX_);
                if (!full0) {
                    const int kp = kt * 64 + (e & 3) + 8 * (e >> 2) + 4 * half;
                    p = (kp <= qa) ? p : 0.f;
                }
                s0[e] = p; sm += p;
            }
            if (act1) {
                const bool full1 = (kt * 64 + 63) <= qb0;
                #pragma unroll
                for (int e = 0; e < 16; ++e) {
                    float p = __builtin_amdgcn_exp2f(s1[e] * SC2_ - MFIX_);
                    if (!full1) {
                        const int kp = kt * 64 + 32 + (e & 3) + 8 * (e >> 2) + 4 * half;
                        p = (kp <= qa) ? p : 0.f;
                    }
                    s1[e] = p; sm += p;
                }
            }
            l_i += sm;

            // P: C-layout -> B-layout via cross-half register exchange
            bf16x8 pf[4];
            {
                uint32_t d0 = pkbf(s0[0],  s0[1]),  d1 = pkbf(s0[2],  s0[3]);
                uint32_t d2 = pkbf(s0[4],  s0[5]),  d3 = pkbf(s0[6],  s0[7]);
                uint32_t d4 = pkbf(s0[8],  s0[9]),  d5 = pkbf(s0[10], s0[11]);
                uint32_t d6 = pkbf(s0[12], s0[13]), d7 = pkbf(s0[14], s0[15]);
                uint32_t x0 = __shfl_xor((int)d0, 32), x1 = __shfl_xor((int)d1, 32);
                uint32_t x2 = __shfl_xor((int)d2, 32), x3 = __shfl_xor((int)d3, 32);
                uint32_t x4 = __shfl_xor((int)d4, 32), x5 = __shfl_xor((int)d5, 32);
                uint32_t x6 = __shfl_xor((int)d6, 32), x7 = __shfl_xor((int)d7, 32);
                pf[0] = half ? mk8(x2, x3, d2, d3) : mk8(d0, d1, x0, x1);
                pf[1] = half ? mk8(x6, x7, d6, d7) : mk8(d4, d5, x4, x5);
            }
            if (act1) {
                uint32_t d0 = pkbf(s1[0],  s1[1]),  d1 = pkbf(s1[2],  s1[3]);
                uint32_t d2 = pkbf(s1[4],  s1[5]),  d3 = pkbf(s1[6],  s1[7]);
                uint32_t d4 = pkbf(s1[8],  s1[9]),  d5 = pkbf(s1[10], s1[11]);
                uint32_t d6 = pkbf(s1[12], s1[13]), d7 = pkbf(s1[14], s1[15]);
                uint32_t x0 = __shfl_xor((int)d0, 32), x1 = __shfl_xor((int)d1, 32);
                uint32_t x2 = __shfl_xor((int)d2, 32), x3 = __shfl_xor((int)d3, 32);
                uint32_t x4 = __shfl_xor((int)d4, 32), x5 = __shfl_xor((int)d5, 32);
                uint32_t x6 = __shfl_xor((int)d6, 32), x7 = __shfl_xor((int)d7, 32);
                pf[2] = half ? mk8(x2, x3, d2, d3) : mk8(d0, d1, x0, x1);
                pf[3] = half ? mk8(x6, x7, d6, d7) : mk8(d4, d5, x4, x5);
            }

            // O^T += V^T * P^T
            const int nc = act1 ? 4 : 2;
            #pragma unroll
            for (int c = 0; c < 4; ++c) {
                if (c >= nc) break;
                #pragma unroll
                for (int dt = 0; dt < 2; ++dt)
                    o_acc[dt] = __builtin_amdgcn_mfma_f32_32x32x16_bf16(
                        vf[dt][c], pf[c], o_acc[dt], 0, 0, 0);
            }
        }
        __syncthreads();
    }

    // epilogue: combine halves of l once, normalize, store O (b, s, h*64+d)
    const float lt = l_i + __shfl_xor(l_i, 32);
    const float inv = 1.f / lt;
    bf16* op = O + ((size_t)(b * S_ + qa) * H_ + h) * DH_;
    #pragma unroll
    for (int dt = 0; dt < 2; ++dt)
        #pragma unroll
        for (int g = 0; g < 4; ++g) {
            bf16x4 ov;
            #pragma unroll
            for (int r = 0; r < 4; ++r) ov[r] = (bf16)(o_acc[dt][g * 4 + r] * inv);
            *(bf16x4*)(op + dt * 32 + g * 8 + half * 4) = ov;
        }
}

// ---------------------------------------------------------------------------
extern "C" void kernel_launch(void* const* d_in, const int* in_sizes, int n_in,
                              void* d_out, int out_size, void* d_ws, size_t ws_size,
                              hipStream_t stream)
{
    const float* X    = (const float*)d_in[0];
    const float* cs   = (const float*)d_in[1];
    const float* sn   = (const float*)d_in[2];
    const float* Wq   = (const float*)d_in[4];
    const float* Wk   = (const float*)d_in[5];
    const float* Wv   = (const float*)d_in[6];
    const float* Wo   = (const float*)d_in[7];
    float* Y          = (float*)d_out;

    bf16* Xb  = (bf16*)d_ws;                       // 8388608
    bf16* Wqb = Xb  + (size_t)8388608;             // 4194304
    bf16* Wkb = Wqb + (size_t)4194304;             // 1048576
    bf16* Wvb = Wkb + (size_t)1048576;             // 1048576
    bf16* Wob = Wvb + (size_t)1048576;             // 4194304
    bf16* Qb  = Wob + (size_t)4194304;             // 8388608
    bf16* Kb  = Qb  + (size_t)8388608;             // 2097152
    bf16* Vtb = Kb  + (size_t)2097152;             // 2097152 (transposed d,s)
    bf16* Ob  = Vtb + (size_t)2097152;             // 8388608

    dim3 blk(256);
    cvt_all_kernel<<<dim3(9216), blk, 0, stream>>>(X, Wq, Wk, Wv, Wo,
                                                   Xb, Wqb, Wkb, Wvb, Wob);
    gemm_qkv_kernel<<<dim3(32, 24), blk, 0, stream>>>(Xb, Wqb, Wkb, Wvb,
                                                      cs, sn, Qb, Kb, Vtb);
    attn_kernel<<<dim3(16, H_, B_), blk, 0, stream>>>(Qb, Kb, Vtb, Ob);
    gemm_out_kernel<<<dim3(32, 16), blk, 0, stream>>>(Ob, Wob, Y);
}